// Round 8
// baseline (186.279 us; speedup 1.0000x reference)
//
#include <hip/hip_runtime.h>
#include <hip/hip_bf16.h>

// ModuleCorefProp2: coref propagation, B=1, K=512, N=16384, D=512, H=64, NB=10, 1 iter.
// R8 = R7 with the all_out copy restored to the R6-proven placement (full copy in
// pair1, BEFORE k_mid2's scatter; pair2 copies nothing). R7's split had pair2
// overwriting scattered rows >= 8192.
//  - epilogue: per-wave LDS tile + MFMA h-reduce vs Wo-col-0 (replaces 5x shfl chains)
//  - right_j folded into K-loop GEMM: V' = u_i*WpT + WrT

typedef __bf16 bf16;
typedef bf16 bf16x8 __attribute__((ext_vector_type(8)));
typedef float f32x4 __attribute__((ext_vector_type(4)));
typedef float f32x16 __attribute__((ext_vector_type(16)));

#define MFMA16(a, b, c) __builtin_amdgcn_mfma_f32_16x16x32_bf16((a), (b), (c), 0, 0, 0)
#define MFMA32(a, b, c) __builtin_amdgcn_mfma_f32_32x32x16_bf16((a), (b), (c), 0, 0, 0)

__device__ __forceinline__ void gll16(const bf16* g, bf16* lds) {
  __builtin_amdgcn_global_load_lds(
      (const __attribute__((address_space(1))) unsigned int*)g,
      (__attribute__((address_space(3))) unsigned int*)lds, 16, 0, 0);
}

// ---------------------------------------------------------------- prep
__global__ void k_prep(const float* __restrict__ sv,
                       const float* __restrict__ Wl, const float* __restrict__ Wr,
                       const float* __restrict__ Wg1, const float* __restrict__ Wg2,
                       const float* __restrict__ de, const float* __restrict__ Wd,
                       const float* __restrict__ bd, const float* __restrict__ bl,
                       const float* __restrict__ br, const float* __restrict__ bg1,
                       const float* __restrict__ bg2, const float* __restrict__ Wp,
                       bf16* __restrict__ u1, bf16* __restrict__ ugb,
                       bf16* __restrict__ wlr, float* __restrict__ blbr,
                       float* __restrict__ bgc, bf16* __restrict__ wgb,
                       float* __restrict__ dtab, bf16* __restrict__ wpTb,
                       bf16* __restrict__ wrTb)
{
  const int total = 262144 + 65536 + 128 + 1048576 + 1024 + 640 + 32768 + 32768;
  for (int idx0 = blockIdx.x * 256 + threadIdx.x; idx0 < total; idx0 += 2048 * 256) {
    int k = idx0;
    if (k < 262144) {                 // u -> bf16, and left halves of gate inputs
      float v = sv[k]; bf16 b = (bf16)v; u1[k] = b;
      int i = k >> 9, d = k & 511;
      ugb[(long)i * 1024 + d] = b;
      ugb[524288 + (long)i * 1024 + d] = b;
      continue;
    }
    k -= 262144;
    if (k < 65536) {                  // Wlr = [Wl | Wr] bf16 [512][128]
      int d = k >> 7, h = k & 127;
      wlr[k] = (bf16)(h < 64 ? Wl[d * 64 + h] : Wr[d * 64 + h - 64]);
      continue;
    }
    k -= 65536;
    if (k < 128) { blbr[k] = (k < 64 ? bl[k] : br[k - 64]); continue; }
    k -= 128;
    if (k < 1048576) {                // Wg1|Wg2 bf16 [2][1024][512]
      wgb[k] = (bf16)(k < 524288 ? Wg1[k] : Wg2[k - 524288]);
      continue;
    }
    k -= 1048576;
    if (k < 1024) { bgc[k] = (k < 512 ? bg1[k] : bg2[k - 512]); continue; }
    k -= 1024;
    if (k < 640) {                    // dtab[NB][64] = dist_emb@Wd + bd
      int b_ = k >> 6, h = k & 63;
      float s = bd[h];
      for (int e = 0; e < 64; ++e) s += de[b_ * 64 + e] * Wd[e * 64 + h];
      dtab[k] = s;
      continue;
    }
    k -= 640;
    if (k < 32768) {                  // wpTb[h][d] = Wp[d][h], bf16 [64][512]
      int h = k >> 9, d = k & 511;
      wpTb[k] = (bf16)Wp[d * 64 + h];
      continue;
    }
    k -= 32768;
    {                                 // wrTb[h][d] = Wr[d][h], bf16 [64][512]
      int h = k >> 9, d = k & 511;
      wrTb[k] = (bf16)Wr[d * 64 + h];
    }
  }
}

// ---------------------------------------------------------------- generic GEMM
__global__ __launch_bounds__(256, 2) void k_gemm(
    const bf16* __restrict__ A, int lda, long asz,
    const bf16* __restrict__ B, int ldb, long bsz,
    float* __restrict__ C, int ldc, long csz,
    const float* __restrict__ bias, int bstride, int K,
    bf16* __restrict__ xout)
{
  __shared__ bf16 As[64 * 40];
  __shared__ bf16 Bs[64 * 40];
  const int t = threadIdx.x, lane = t & 63, wave = t >> 6;
  const int tc = blockIdx.x, tr = blockIdx.y, z = blockIdx.z;
  A += (long)z * asz; B += (long)z * bsz; C += (long)z * csz;
  const int wr = wave >> 1, wc = wave & 1;
  const int arow = t >> 2, aslot = t & 3;
  const int s = lane >> 4, rr = lane & 15;
  f32x4 acc00 = {}, acc01 = {}, acc10 = {}, acc11 = {};
  const int nk = K >> 5;
  for (int kk = 0; kk < nk; ++kk) {
    __syncthreads();
    *(uint4*)&As[arow * 40 + aslot * 8] =
        *(const uint4*)(A + (long)(tr * 64 + arow) * lda + kk * 32 + aslot * 8);
    {
      const bf16* bsrc = B + (long)(kk * 32 + aslot * 8) * ldb + tc * 64 + arow;
      bf16x8 tv;
#pragma unroll
      for (int e = 0; e < 8; ++e) tv[e] = bsrc[(long)e * ldb];
      *(bf16x8*)&Bs[arow * 40 + aslot * 8] = tv;
    }
    __syncthreads();
    bf16x8 a0 = *(const bf16x8*)&As[(wr * 32 + rr) * 40 + s * 8];
    bf16x8 a1 = *(const bf16x8*)&As[(wr * 32 + 16 + rr) * 40 + s * 8];
    bf16x8 b0 = *(const bf16x8*)&Bs[(wc * 32 + rr) * 40 + s * 8];
    bf16x8 b1 = *(const bf16x8*)&Bs[(wc * 32 + 16 + rr) * 40 + s * 8];
    acc00 = MFMA16(a0, b0, acc00);
    acc01 = MFMA16(a0, b1, acc01);
    acc10 = MFMA16(a1, b0, acc10);
    acc11 = MFMA16(a1, b1, acc11);
  }
#pragma unroll
  for (int mf = 0; mf < 2; ++mf) {
#pragma unroll
    for (int nf = 0; nf < 2; ++nf) {
      f32x4 v = mf == 0 ? (nf == 0 ? acc00 : acc01) : (nf == 0 ? acc10 : acc11);
      int col = tc * 64 + wc * 32 + nf * 16 + rr;
      float bi = bias ? bias[z * bstride + col] : 0.f;
      int row0 = tr * 64 + wr * 32 + mf * 16 + s * 4;
#pragma unroll
      for (int r = 0; r < 4; ++r) {
        float val = v[r] + bi;
        int row = row0 + r;
        C[(long)row * ldc + col] = val;
        if (xout) {
          long gidx = (row < 512)
              ? ((long)row * 1024 + 512 + col)
              : (524288 + (long)(row - 512) * 1024 + 512 + col);
          xout[gidx] = (bf16)val;
        }
      }
    }
  }
}

// ---------------------------------------------------------------- fused pair scorer (R8)
// One WG per i; 8 waves; wave w owns j in [w*64, w*64+64). K-loop as R5.
// V' = u_i*WpT + WrT (GEMM result = prod + right_j).
// Epilogue: relu'd bf16 tile -> per-wave LDS (swizzled) -> MFMA h-reduce vs Wo col-0.
// docopy=1 (pair1 only): full all_span_vecs -> out_all copy at tail (BEFORE mid2 scatter).
__global__ __launch_bounds__(512, 2) void k_pair(
    const bf16* __restrict__ Ubf, const float* __restrict__ Uf,
    const bf16* __restrict__ wpTb, const bf16* __restrict__ wrTb,
    const float* __restrict__ LR, const float* __restrict__ dtabg,
    const int* __restrict__ sb, const float* __restrict__ ss,
    const float* __restrict__ Wo, const float* __restrict__ bo,
    const float* __restrict__ Br, float* __restrict__ cs,
    const float* __restrict__ copysrc, float* __restrict__ copydst, int docopy)
{
  __shared__ bf16 As[2][512 * 32];  // 2 x 32KB, row = 64B = 4 x 16B slots
  __shared__ bf16 Vs[2][64 * 32];   // 2 x 4KB
  __shared__ float uil[512];
  __shared__ float dts[640];

  const int t = threadIdx.x;
  const int l = t & 63;
  const int w = t >> 6;
  const int i = blockIdx.x;
  const int half = l >> 5;
  const int l31 = l & 31;

  // ---- prologue: u_i row (f32) + dist table
  if (t < 128) {
    float4 v = *(const float4*)(Uf + (long)i * 512 + t * 4);
    *(float4*)&uil[t * 4] = v;
  }
  for (int idx = t; idx < 640; idx += 512) dts[idx] = dtabg[idx];

  const bf16 *asrc0, *asrc1, *asrc2, *asrc3;
  {
    int rq0 = 0 * 128 + (t >> 2), rq1 = 1 * 128 + (t >> 2);
    int rq2 = 2 * 128 + (t >> 2), rq3 = 3 * 128 + (t >> 2);
    asrc0 = Ubf + (long)rq0 * 512 + (((t & 3) ^ ((rq0 >> 1) & 3)) * 8);
    asrc1 = Ubf + (long)rq1 * 512 + (((t & 3) ^ ((rq1 >> 1) & 3)) * 8);
    asrc2 = Ubf + (long)rq2 * 512 + (((t & 3) ^ ((rq2 >> 1) & 3)) * 8);
    asrc3 = Ubf + (long)rq3 * 512 + (((t & 3) ^ ((rq3 >> 1) & 3)) * 8);
  }
  int aoff[2][2], voff[2][2];
#pragma unroll
  for (int jf = 0; jf < 2; ++jf)
#pragma unroll
    for (int ks = 0; ks < 2; ++ks) {
      int r = w * 64 + jf * 32 + l31;
      aoff[jf][ks] = r * 64 + (((ks * 2 + half) ^ ((r >> 1) & 3)) * 16);
    }
#pragma unroll
  for (int hf = 0; hf < 2; ++hf)
#pragma unroll
    for (int ks = 0; ks < 2; ++ks) {
      int h = hf * 32 + l31;
      voff[hf][ks] = h * 64 + (((ks * 2 + half) ^ ((h >> 1) & 3)) * 16);
    }
  const int vh = t >> 2;
  const int vcp = (t & 3) ^ ((vh >> 1) & 3);

  __syncthreads();   // uil visible before V builds

  // ---- stage chunk 0 into buf 0
  gll16(asrc0, &As[0][0 * 4096 + w * 512]);
  gll16(asrc1, &As[0][1 * 4096 + w * 512]);
  gll16(asrc2, &As[0][2 * 4096 + w * 512]);
  gll16(asrc3, &As[0][3 * 4096 + w * 512]);
  if (t < 256) {
    bf16x8 wv = *(const bf16x8*)(wpTb + (long)vh * 512 + vcp * 8);
    bf16x8 wr8 = *(const bf16x8*)(wrTb + (long)vh * 512 + vcp * 8);
    float4 u0 = *(const float4*)&uil[vcp * 8];
    float4 u1 = *(const float4*)&uil[vcp * 8 + 4];
    bf16x8 sv8;
#pragma unroll
    for (int e = 0; e < 4; ++e) {
      sv8[e] = (bf16)((float)wv[e] * u0[e] + (float)wr8[e]);
      sv8[e + 4] = (bf16)((float)wv[e + 4] * u1[e] + (float)wr8[e + 4]);
    }
    *(bf16x8*)((char*)&Vs[0][0] + vh * 64 + (t & 3) * 16) = sv8;
  }
  asm volatile("s_waitcnt vmcnt(0)");
  __syncthreads();

  f32x16 acc[2][2] = {};

  for (int kc = 0; kc < 16; ++kc) {
    const int cur = kc & 1;
    if (kc < 15) {
      gll16(asrc0 + (kc + 1) * 32, &As[cur ^ 1][0 * 4096 + w * 512]);
      gll16(asrc1 + (kc + 1) * 32, &As[cur ^ 1][1 * 4096 + w * 512]);
      gll16(asrc2 + (kc + 1) * 32, &As[cur ^ 1][2 * 4096 + w * 512]);
      gll16(asrc3 + (kc + 1) * 32, &As[cur ^ 1][3 * 4096 + w * 512]);
      if (t < 256) {
        bf16x8 wv = *(const bf16x8*)(wpTb + (long)vh * 512 + (kc + 1) * 32 + vcp * 8);
        bf16x8 wr8 = *(const bf16x8*)(wrTb + (long)vh * 512 + (kc + 1) * 32 + vcp * 8);
        float4 u0 = *(const float4*)&uil[(kc + 1) * 32 + vcp * 8];
        float4 u1 = *(const float4*)&uil[(kc + 1) * 32 + vcp * 8 + 4];
        bf16x8 sv8;
#pragma unroll
        for (int e = 0; e < 4; ++e) {
          sv8[e] = (bf16)((float)wv[e] * u0[e] + (float)wr8[e]);
          sv8[e + 4] = (bf16)((float)wv[e + 4] * u1[e] + (float)wr8[e + 4]);
        }
        *(bf16x8*)((char*)&Vs[cur ^ 1][0] + vh * 64 + (t & 3) * 16) = sv8;
      }
    }
    const char* Asb = (const char*)&As[cur][0];
    const char* Vsb = (const char*)&Vs[cur][0];
#pragma unroll
    for (int ks = 0; ks < 2; ++ks) {
      bf16x8 af0 = *(const bf16x8*)(Asb + aoff[0][ks]);
      bf16x8 af1 = *(const bf16x8*)(Asb + aoff[1][ks]);
      bf16x8 vf0 = *(const bf16x8*)(Vsb + voff[0][ks]);
      bf16x8 vf1 = *(const bf16x8*)(Vsb + voff[1][ks]);
      __builtin_amdgcn_s_setprio(1);
      acc[0][0] = MFMA32(af0, vf0, acc[0][0]);
      acc[0][1] = MFMA32(af0, vf1, acc[0][1]);
      acc[1][0] = MFMA32(af1, vf0, acc[1][0]);
      acc[1][1] = MFMA32(af1, vf1, acc[1][1]);
      __builtin_amdgcn_s_setprio(0);
    }
    if (kc < 15) asm volatile("s_waitcnt vmcnt(0)");
    __syncthreads();
  }

  // ---- epilogue v2: add left+br+dist, relu -> per-wave bf16 LDS tile -> MFMA h-reduce
  const float lf0 = LR[i * 128 + l31] + Br[l31];
  const float lf1 = LR[i * 128 + 32 + l31] + Br[32 + l31];
  bf16x8 wob[4];
#pragma unroll
  for (int c = 0; c < 4; ++c) {
#pragma unroll
    for (int e = 0; e < 8; ++e)
      wob[c][e] = (l31 == 0) ? (bf16)Wo[c * 16 + half * 8 + e] : (bf16)0.f;
  }
  const int sbi = sb[i];
  const float ssi = ss[i];
  const float bo0 = bo[0];
  char* T = (char*)&As[0][0] + w * 4096;   // per-wave 4KB scratch (safe after last barrier)

#pragma unroll
  for (int jf = 0; jf < 2; ++jf) {
    // phase 1: write relu'd bf16 tile T[32 rows][64 h], slot-swizzled
#pragma unroll
    for (int r = 0; r < 16; ++r) {
      int jl = (r & 3) + 8 * (r >> 2) + 4 * half;
      int j = w * 64 + jf * 32 + jl;
      int dd = sbi - sb[j];
      int ad = dd < 0 ? -dd : dd;
      int bkt = ad < 5 ? ad : (31 - __clz(ad)) + 3;
      bkt = bkt > 9 ? 9 : bkt;
      float v0 = fmaxf(acc[jf][0][r] + lf0 + dts[bkt * 64 + l31], 0.f);
      float v1 = fmaxf(acc[jf][1][r] + lf1 + dts[bkt * 64 + 32 + l31], 0.f);
      char* rowp = T + jl * 128;
      *(bf16*)(rowp + (((l31 >> 3) ^ (jl & 7)) * 16) + (l31 & 7) * 2) = (bf16)v0;
      *(bf16*)(rowp + ((((l31 >> 3) + 4) ^ (jl & 7)) * 16) + (l31 & 7) * 2) = (bf16)v1;
    }
    asm volatile("s_waitcnt lgkmcnt(0)" ::: "memory");
    __builtin_amdgcn_sched_barrier(0);
    // phase 2: h-reduce via MFMA against Wo (col 0)
    f32x16 acc2 = {};
#pragma unroll
    for (int c = 0; c < 4; ++c) {
      bf16x8 afr = *(const bf16x8*)(T + l31 * 128 + (((c * 2 + half) ^ (l31 & 7)) * 16));
      acc2 = MFMA32(afr, wob[c], acc2);
    }
    // phase 3: col-0 lanes finalize and write
    if (l31 == 0) {
#pragma unroll
      for (int r = 0; r < 16; ++r) {
        int jl = (r & 3) + 8 * (r >> 2) + 4 * half;
        int j = w * 64 + jf * 32 + jl;
        float val = acc2[r] + bo0 + ssi + ss[j];
        cs[(long)i * 512 + j] = (j == i) ? 0.f : val;
      }
    }
    asm volatile("s_waitcnt lgkmcnt(0)" ::: "memory");
    __builtin_amdgcn_sched_barrier(0);
  }

  // ---- folded FULL all_span_vecs copy (pair1 only; must precede mid2's scatter)
  if (docopy) {
    const float4* s4 = (const float4*)copysrc;
    float4* d4 = (float4*)copydst;
    int idx = i * 512 + t;               // 262144 threads
#pragma unroll
    for (int q = 0; q < 8; ++q)
      d4[(long)q * 262144 + idx] = s4[(long)q * 262144 + idx];
  }
}

// ---------------------------------------------------------------- masked softmax rows
__global__ __launch_bounds__(64) void k_softmax(const float* __restrict__ cs,
                                                bf16* __restrict__ p12)
{
  int b = blockIdx.x, kind = b >> 9, i = b & 511, lane = threadIdx.x;
  const float* row = cs + i * 512;
  float v[8];
  float4 x0 = *(const float4*)(row + lane * 8);
  float4 x1 = *(const float4*)(row + lane * 8 + 4);
  v[0] = x0.x; v[1] = x0.y; v[2] = x0.z; v[3] = x0.w;
  v[4] = x1.x; v[5] = x1.y; v[6] = x1.z; v[7] = x1.w;
  bool any = (kind == 0) ? (i > 0) : (i < 511);
  bf16x8 ov;
  if (!any) {
    float u = 1.0f / 512.0f;
#pragma unroll
    for (int e = 0; e < 8; ++e) ov[e] = (bf16)u;
  } else {
    float m = -3.4e38f;
#pragma unroll
    for (int e = 0; e < 8; ++e) {
      int jj = lane * 8 + e;
      bool valid = (kind == 0) ? (jj < i) : (jj > i);
      if (valid) m = fmaxf(m, v[e]);
    }
    m = fmaxf(m, __shfl_xor(m, 1));  m = fmaxf(m, __shfl_xor(m, 2));
    m = fmaxf(m, __shfl_xor(m, 4));  m = fmaxf(m, __shfl_xor(m, 8));
    m = fmaxf(m, __shfl_xor(m, 16)); m = fmaxf(m, __shfl_xor(m, 32));
    float p[8]; float ssum = 0.f;
#pragma unroll
    for (int e = 0; e < 8; ++e) {
      int jj = lane * 8 + e;
      bool valid = (kind == 0) ? (jj < i) : (jj > i);
      p[e] = valid ? __expf(v[e] - m) : 0.f;
      ssum += p[e];
    }
    ssum += __shfl_xor(ssum, 1);  ssum += __shfl_xor(ssum, 2);
    ssum += __shfl_xor(ssum, 4);  ssum += __shfl_xor(ssum, 8);
    ssum += __shfl_xor(ssum, 16); ssum += __shfl_xor(ssum, 32);
    float inv = 1.0f / ssum;
#pragma unroll
    for (int e = 0; e < 8; ++e) ov[e] = (bf16)(p[e] * inv);
  }
  *(bf16x8*)(p12 + (long)b * 512 + lane * 8) = ov;
}

// ---------------------------------------------------------------- mid2: gate+ss2+lr2+scatter
__global__ __launch_bounds__(512) void k_mid2(
    const float* __restrict__ sv, const float* __restrict__ c12,
    const float* __restrict__ G12, const float* __restrict__ Wpr,
    const float* __restrict__ bpr, const bf16* __restrict__ wlr,
    const float* __restrict__ blbr, const int* __restrict__ pi,
    const int* __restrict__ sl, float* __restrict__ upd,
    bf16* __restrict__ u2, float* __restrict__ ss2,
    float* __restrict__ lr2, float* __restrict__ out_all)
{
  __shared__ float upl[512];
  __shared__ float red[8];
  __shared__ float part2[4][128];
  const int i = blockIdx.x;
  const int t = threadIdx.x;
  const long ii = (long)i * 512 + t;

  float u = sv[ii], c1 = c12[ii], c2 = c12[262144 + ii];
  float g1 = 1.f / (1.f + __expf(-G12[ii]));
  float g2 = 1.f / (1.f + __expf(-G12[262144 + ii]));
  float up = g1 * u + (1.f - g1) * c1 + g2 * u + (1.f - g2) * c2;
  upd[ii] = up;
  u2[ii] = (bf16)up;
  upl[t] = up;
  if (i < sl[0]) out_all[(long)pi[i] * 512 + t] = up;   // scatter (out_all pre-filled)

  // ss2 = dot(up, Wpr) + bpr
  float pd = up * Wpr[t];
  pd += __shfl_xor(pd, 1);  pd += __shfl_xor(pd, 2);  pd += __shfl_xor(pd, 4);
  pd += __shfl_xor(pd, 8);  pd += __shfl_xor(pd, 16); pd += __shfl_xor(pd, 32);
  if ((t & 63) == 0) red[t >> 6] = pd;
  __syncthreads();
  if (t == 0) {
    float s = 0.f;
#pragma unroll
    for (int e = 0; e < 8; ++e) s += red[e];
    ss2[i] = s + bpr[0];
  }

  // lr2[i][n] = sum_d up[d]*wlr[d][n] + blbr[n]
  const int n = t & 127, part = t >> 7;
  float s = 0.f;
  const int d0 = part * 128;
#pragma unroll 4
  for (int d2 = 0; d2 < 128; ++d2)
    s += upl[d0 + d2] * (float)wlr[(d0 + d2) * 128 + n];
  part2[part][n] = s;
  __syncthreads();
  if (t < 128)
    lr2[(long)i * 128 + t] =
        part2[0][t] + part2[1][t] + part2[2][t] + part2[3][t] + blbr[t];
}

// ---------------------------------------------------------------- launch
extern "C" void kernel_launch(void* const* d_in, const int* in_sizes, int n_in,
                              void* d_out, int out_size, void* d_ws, size_t ws_size,
                              hipStream_t stream)
{
  const float* asv = (const float*)d_in[0];
  const float* sv = (const float*)d_in[1];
  const int* sb = (const int*)d_in[2];
  const float* sscore = (const float*)d_in[5];
  const int* pi = (const int*)d_in[6];
  const int* sl = (const int*)d_in[7];
  const float* Wl = (const float*)d_in[9];
  const float* bl = (const float*)d_in[10];
  const float* Wr = (const float*)d_in[11];
  const float* br = (const float*)d_in[12];
  const float* Wp = (const float*)d_in[13];
  const float* de = (const float*)d_in[14];
  const float* Wd = (const float*)d_in[15];
  const float* bd = (const float*)d_in[16];
  const float* Wo = (const float*)d_in[17];
  const float* bo = (const float*)d_in[18];
  const float* Wg1 = (const float*)d_in[19];
  const float* bg1 = (const float*)d_in[20];
  const float* Wg2 = (const float*)d_in[21];
  const float* bg2 = (const float*)d_in[22];
  const float* Wpr = (const float*)d_in[23];
  const float* bpr = (const float*)d_in[24];

  float* out_all = (float*)d_out;
  float* out_upd = out_all + 8388608;   // [512][512] update
  float* out_cs = out_all + 8650752;    // [512][512] cs

  char* w = (char*)d_ws;
  size_t off = 0;
  auto take = [&](size_t bytes) -> void* {
    void* p = w + off;
    off = (off + bytes + 255) & ~(size_t)255;
    return p;
  };
  bf16* u1b = (bf16*)take(524288);
  bf16* u2b = (bf16*)take(524288);
  bf16* wlr = (bf16*)take(131072);
  bf16* wgb = (bf16*)take(2097152);
  float* blbr = (float*)take(512);
  float* bgc = (float*)take(4096);
  float* dtab = (float*)take(2560);
  bf16* wpTb = (bf16*)take(65536);
  bf16* wrTb = (bf16*)take(65536);
  float* lr1 = (float*)take(262144);
  float* lr2 = (float*)take(262144);
  float* cs1 = (float*)take(1048576);
  bf16* p12 = (bf16*)take(1048576);
  float* c12 = (float*)take(4194304);
  bf16* ugb = (bf16*)take(2097152);
  float* G12 = (float*)take(2097152);
  float* ss2 = (float*)take(2048);

  k_prep<<<2048, 256, 0, stream>>>(sv, Wl, Wr, Wg1, Wg2, de, Wd, bd, bl, br, bg1, bg2,
                                   Wp, u1b, ugb, wlr, blbr, bgc, wgb, dtab, wpTb, wrTb);
  // left|right for u
  k_gemm<<<dim3(2, 8, 1), 256, 0, stream>>>(u1b, 512, 0, wlr, 128, 0, lr1, 128, 0,
                                            blbr, 0, 512, nullptr);
  // cs1 = add_scores(pair_scores(u), span_scores); + full all_out copy (pre-scatter)
  k_pair<<<512, 512, 0, stream>>>(u1b, sv, wpTb, wrTb, lr1, dtab, sb, sscore, Wo, bo,
                                  br, cs1, asv, out_all, 1);
  // p1,p2
  k_softmax<<<1024, 64, 0, stream>>>(cs1, p12);
  // c1,c2 = [p1;p2] @ u ; epilogue also fills ugb right halves (bf16)
  k_gemm<<<dim3(8, 16, 1), 256, 0, stream>>>(p12, 512, 0, u1b, 512, 0, c12, 512, 0,
                                             nullptr, 0, 512, ugb);
  // G1,G2 = [u|c] @ Wg + bg   (batched z=2, K=1024)
  k_gemm<<<dim3(8, 8, 2), 256, 0, stream>>>(ugb, 1024, 524288, wgb, 512, 524288,
                                            G12, 512, 262144, bgc, 512, 1024, nullptr);
  // update + u2 bf16 + ss2 + lr2 + scatter (fused)
  k_mid2<<<512, 512, 0, stream>>>(sv, c12, G12, Wpr, bpr, wlr, blbr, pi, sl,
                                  out_upd, u2b, ss2, lr2, out_all);
  // cs = add_scores(pair_scores(update), update@Wpr+bpr)
  k_pair<<<512, 512, 0, stream>>>(u2b, out_upd, wpTb, wrTb, lr2, dtab, sb, ss2, Wo, bo,
                                  br, out_cs, nullptr, nullptr, 0);
}

// Round 9
// 158.526 us; speedup vs baseline: 1.1751x; 1.1751x over previous
//
#include <hip/hip_runtime.h>
#include <hip/hip_bf16.h>

// ModuleCorefProp2: coref propagation, B=1, K=512, N=16384, D=512, H=64, NB=10, 1 iter.
// R9: R6-proven k_pair core (shfl epilogue) + R8's wrT-fold kept (V' = u_i*WpT + WrT)
//  + softmax fused into pair1 epilogue (cs row staged in LDS; waves 0/1 compute p1/p2)
//  + pair2 writes out_cs coalesced from the LDS row
//  + cs1 buffer and k_softmax dispatch deleted (7 dispatches).

typedef __bf16 bf16;
typedef bf16 bf16x8 __attribute__((ext_vector_type(8)));
typedef float f32x4 __attribute__((ext_vector_type(4)));
typedef float f32x16 __attribute__((ext_vector_type(16)));

#define MFMA16(a, b, c) __builtin_amdgcn_mfma_f32_16x16x32_bf16((a), (b), (c), 0, 0, 0)
#define MFMA32(a, b, c) __builtin_amdgcn_mfma_f32_32x32x16_bf16((a), (b), (c), 0, 0, 0)

__device__ __forceinline__ void gll16(const bf16* g, bf16* lds) {
  __builtin_amdgcn_global_load_lds(
      (const __attribute__((address_space(1))) unsigned int*)g,
      (__attribute__((address_space(3))) unsigned int*)lds, 16, 0, 0);
}

// ---------------------------------------------------------------- prep
__global__ void k_prep(const float* __restrict__ sv,
                       const float* __restrict__ Wl, const float* __restrict__ Wr,
                       const float* __restrict__ Wg1, const float* __restrict__ Wg2,
                       const float* __restrict__ de, const float* __restrict__ Wd,
                       const float* __restrict__ bd, const float* __restrict__ bl,
                       const float* __restrict__ br, const float* __restrict__ bg1,
                       const float* __restrict__ bg2, const float* __restrict__ Wp,
                       bf16* __restrict__ u1, bf16* __restrict__ ugb,
                       bf16* __restrict__ wlr, float* __restrict__ blbr,
                       float* __restrict__ bgc, bf16* __restrict__ wgb,
                       float* __restrict__ dtab, bf16* __restrict__ wpTb,
                       bf16* __restrict__ wrTb)
{
  const int total = 262144 + 65536 + 128 + 1048576 + 1024 + 640 + 32768 + 32768;
  for (int idx0 = blockIdx.x * 256 + threadIdx.x; idx0 < total; idx0 += 2048 * 256) {
    int k = idx0;
    if (k < 262144) {                 // u -> bf16, and left halves of gate inputs
      float v = sv[k]; bf16 b = (bf16)v; u1[k] = b;
      int i = k >> 9, d = k & 511;
      ugb[(long)i * 1024 + d] = b;
      ugb[524288 + (long)i * 1024 + d] = b;
      continue;
    }
    k -= 262144;
    if (k < 65536) {                  // Wlr = [Wl | Wr] bf16 [512][128]
      int d = k >> 7, h = k & 127;
      wlr[k] = (bf16)(h < 64 ? Wl[d * 64 + h] : Wr[d * 64 + h - 64]);
      continue;
    }
    k -= 65536;
    if (k < 128) { blbr[k] = (k < 64 ? bl[k] : br[k - 64]); continue; }
    k -= 128;
    if (k < 1048576) {                // Wg1|Wg2 bf16 [2][1024][512]
      wgb[k] = (bf16)(k < 524288 ? Wg1[k] : Wg2[k - 524288]);
      continue;
    }
    k -= 1048576;
    if (k < 1024) { bgc[k] = (k < 512 ? bg1[k] : bg2[k - 512]); continue; }
    k -= 1024;
    if (k < 640) {                    // dtab[NB][64] = dist_emb@Wd + bd
      int b_ = k >> 6, h = k & 63;
      float s = bd[h];
      for (int e = 0; e < 64; ++e) s += de[b_ * 64 + e] * Wd[e * 64 + h];
      dtab[k] = s;
      continue;
    }
    k -= 640;
    if (k < 32768) {                  // wpTb[h][d] = Wp[d][h], bf16 [64][512]
      int h = k >> 9, d = k & 511;
      wpTb[k] = (bf16)Wp[d * 64 + h];
      continue;
    }
    k -= 32768;
    {                                 // wrTb[h][d] = Wr[d][h], bf16 [64][512]
      int h = k >> 9, d = k & 511;
      wrTb[k] = (bf16)Wr[d * 64 + h];
    }
  }
}

// ---------------------------------------------------------------- generic GEMM
__global__ __launch_bounds__(256, 2) void k_gemm(
    const bf16* __restrict__ A, int lda, long asz,
    const bf16* __restrict__ B, int ldb, long bsz,
    float* __restrict__ C, int ldc, long csz,
    const float* __restrict__ bias, int bstride, int K,
    bf16* __restrict__ xout)
{
  __shared__ bf16 As[64 * 40];
  __shared__ bf16 Bs[64 * 40];
  const int t = threadIdx.x, lane = t & 63, wave = t >> 6;
  const int tc = blockIdx.x, tr = blockIdx.y, z = blockIdx.z;
  A += (long)z * asz; B += (long)z * bsz; C += (long)z * csz;
  const int wr = wave >> 1, wc = wave & 1;
  const int arow = t >> 2, aslot = t & 3;
  const int s = lane >> 4, rr = lane & 15;
  f32x4 acc00 = {}, acc01 = {}, acc10 = {}, acc11 = {};
  const int nk = K >> 5;
  for (int kk = 0; kk < nk; ++kk) {
    __syncthreads();
    *(uint4*)&As[arow * 40 + aslot * 8] =
        *(const uint4*)(A + (long)(tr * 64 + arow) * lda + kk * 32 + aslot * 8);
    {
      const bf16* bsrc = B + (long)(kk * 32 + aslot * 8) * ldb + tc * 64 + arow;
      bf16x8 tv;
#pragma unroll
      for (int e = 0; e < 8; ++e) tv[e] = bsrc[(long)e * ldb];
      *(bf16x8*)&Bs[arow * 40 + aslot * 8] = tv;
    }
    __syncthreads();
    bf16x8 a0 = *(const bf16x8*)&As[(wr * 32 + rr) * 40 + s * 8];
    bf16x8 a1 = *(const bf16x8*)&As[(wr * 32 + 16 + rr) * 40 + s * 8];
    bf16x8 b0 = *(const bf16x8*)&Bs[(wc * 32 + rr) * 40 + s * 8];
    bf16x8 b1 = *(const bf16x8*)&Bs[(wc * 32 + 16 + rr) * 40 + s * 8];
    acc00 = MFMA16(a0, b0, acc00);
    acc01 = MFMA16(a0, b1, acc01);
    acc10 = MFMA16(a1, b0, acc10);
    acc11 = MFMA16(a1, b1, acc11);
  }
#pragma unroll
  for (int mf = 0; mf < 2; ++mf) {
#pragma unroll
    for (int nf = 0; nf < 2; ++nf) {
      f32x4 v = mf == 0 ? (nf == 0 ? acc00 : acc01) : (nf == 0 ? acc10 : acc11);
      int col = tc * 64 + wc * 32 + nf * 16 + rr;
      float bi = bias ? bias[z * bstride + col] : 0.f;
      int row0 = tr * 64 + wr * 32 + mf * 16 + s * 4;
#pragma unroll
      for (int r = 0; r < 4; ++r) {
        float val = v[r] + bi;
        int row = row0 + r;
        C[(long)row * ldc + col] = val;
        if (xout) {
          long gidx = (row < 512)
              ? ((long)row * 1024 + 512 + col)
              : (524288 + (long)(row - 512) * 1024 + 512 + col);
          xout[gidx] = (bf16)val;
        }
      }
    }
  }
}

// ---------------------------------------------------------------- fused pair scorer (R9)
// One WG per i; 8 waves; wave w owns j in [w*64, w*64+64). K-loop as R5/R6.
// V' = u_i*WpT + WrT (GEMM result = prod + right_j). Shfl epilogue -> LDS row csrow.
// dosm=1: waves 0/1 compute masked softmax rows -> p12; no cs write (pair1).
// dosm=0: coalesced out_cs row write from csrow (pair2).
// docopy=1: full all_span_vecs -> out_all copy at tail (pair1; precedes mid2 scatter).
__global__ __launch_bounds__(512, 2) void k_pair(
    const bf16* __restrict__ Ubf, const float* __restrict__ Uf,
    const bf16* __restrict__ wpTb, const bf16* __restrict__ wrTb,
    const float* __restrict__ LR, const float* __restrict__ dtabg,
    const int* __restrict__ sb, const float* __restrict__ ss,
    const float* __restrict__ Wo, const float* __restrict__ bo,
    const float* __restrict__ Br, float* __restrict__ cs,
    bf16* __restrict__ p12, int dosm,
    const float* __restrict__ copysrc, float* __restrict__ copydst, int docopy)
{
  __shared__ bf16 As[2][512 * 32];  // 2 x 32KB, row = 64B = 4 x 16B slots
  __shared__ bf16 Vs[2][64 * 32];   // 2 x 4KB
  __shared__ float uil[512];
  __shared__ float dts[640];
  __shared__ float csrow[512];

  const int t = threadIdx.x;
  const int l = t & 63;
  const int w = t >> 6;
  const int i = blockIdx.x;
  const int half = l >> 5;
  const int l31 = l & 31;

  // ---- prologue: u_i row (f32) + dist table
  if (t < 128) {
    float4 v = *(const float4*)(Uf + (long)i * 512 + t * 4);
    *(float4*)&uil[t * 4] = v;
  }
  for (int idx = t; idx < 640; idx += 512) dts[idx] = dtabg[idx];

  const bf16 *asrc0, *asrc1, *asrc2, *asrc3;
  {
    int rq0 = 0 * 128 + (t >> 2), rq1 = 1 * 128 + (t >> 2);
    int rq2 = 2 * 128 + (t >> 2), rq3 = 3 * 128 + (t >> 2);
    asrc0 = Ubf + (long)rq0 * 512 + (((t & 3) ^ ((rq0 >> 1) & 3)) * 8);
    asrc1 = Ubf + (long)rq1 * 512 + (((t & 3) ^ ((rq1 >> 1) & 3)) * 8);
    asrc2 = Ubf + (long)rq2 * 512 + (((t & 3) ^ ((rq2 >> 1) & 3)) * 8);
    asrc3 = Ubf + (long)rq3 * 512 + (((t & 3) ^ ((rq3 >> 1) & 3)) * 8);
  }
  int aoff[2][2], voff[2][2];
#pragma unroll
  for (int jf = 0; jf < 2; ++jf)
#pragma unroll
    for (int ks = 0; ks < 2; ++ks) {
      int r = w * 64 + jf * 32 + l31;
      aoff[jf][ks] = r * 64 + (((ks * 2 + half) ^ ((r >> 1) & 3)) * 16);
    }
#pragma unroll
  for (int hf = 0; hf < 2; ++hf)
#pragma unroll
    for (int ks = 0; ks < 2; ++ks) {
      int h = hf * 32 + l31;
      voff[hf][ks] = h * 64 + (((ks * 2 + half) ^ ((h >> 1) & 3)) * 16);
    }
  const int vh = t >> 2;
  const int vcp = (t & 3) ^ ((vh >> 1) & 3);

  __syncthreads();   // uil visible before V builds

  // ---- stage chunk 0 into buf 0
  gll16(asrc0, &As[0][0 * 4096 + w * 512]);
  gll16(asrc1, &As[0][1 * 4096 + w * 512]);
  gll16(asrc2, &As[0][2 * 4096 + w * 512]);
  gll16(asrc3, &As[0][3 * 4096 + w * 512]);
  if (t < 256) {
    bf16x8 wv = *(const bf16x8*)(wpTb + (long)vh * 512 + vcp * 8);
    bf16x8 wr8 = *(const bf16x8*)(wrTb + (long)vh * 512 + vcp * 8);
    float4 u0 = *(const float4*)&uil[vcp * 8];
    float4 u1 = *(const float4*)&uil[vcp * 8 + 4];
    bf16x8 sv8;
#pragma unroll
    for (int e = 0; e < 4; ++e) {
      sv8[e] = (bf16)((float)wv[e] * u0[e] + (float)wr8[e]);
      sv8[e + 4] = (bf16)((float)wv[e + 4] * u1[e] + (float)wr8[e + 4]);
    }
    *(bf16x8*)((char*)&Vs[0][0] + vh * 64 + (t & 3) * 16) = sv8;
  }
  asm volatile("s_waitcnt vmcnt(0)");
  __syncthreads();

  f32x16 acc[2][2] = {};

  for (int kc = 0; kc < 16; ++kc) {
    const int cur = kc & 1;
    if (kc < 15) {
      gll16(asrc0 + (kc + 1) * 32, &As[cur ^ 1][0 * 4096 + w * 512]);
      gll16(asrc1 + (kc + 1) * 32, &As[cur ^ 1][1 * 4096 + w * 512]);
      gll16(asrc2 + (kc + 1) * 32, &As[cur ^ 1][2 * 4096 + w * 512]);
      gll16(asrc3 + (kc + 1) * 32, &As[cur ^ 1][3 * 4096 + w * 512]);
      if (t < 256) {
        bf16x8 wv = *(const bf16x8*)(wpTb + (long)vh * 512 + (kc + 1) * 32 + vcp * 8);
        bf16x8 wr8 = *(const bf16x8*)(wrTb + (long)vh * 512 + (kc + 1) * 32 + vcp * 8);
        float4 u0 = *(const float4*)&uil[(kc + 1) * 32 + vcp * 8];
        float4 u1 = *(const float4*)&uil[(kc + 1) * 32 + vcp * 8 + 4];
        bf16x8 sv8;
#pragma unroll
        for (int e = 0; e < 4; ++e) {
          sv8[e] = (bf16)((float)wv[e] * u0[e] + (float)wr8[e]);
          sv8[e + 4] = (bf16)((float)wv[e + 4] * u1[e] + (float)wr8[e + 4]);
        }
        *(bf16x8*)((char*)&Vs[cur ^ 1][0] + vh * 64 + (t & 3) * 16) = sv8;
      }
    }
    const char* Asb = (const char*)&As[cur][0];
    const char* Vsb = (const char*)&Vs[cur][0];
#pragma unroll
    for (int ks = 0; ks < 2; ++ks) {
      bf16x8 af0 = *(const bf16x8*)(Asb + aoff[0][ks]);
      bf16x8 af1 = *(const bf16x8*)(Asb + aoff[1][ks]);
      bf16x8 vf0 = *(const bf16x8*)(Vsb + voff[0][ks]);
      bf16x8 vf1 = *(const bf16x8*)(Vsb + voff[1][ks]);
      __builtin_amdgcn_s_setprio(1);
      acc[0][0] = MFMA32(af0, vf0, acc[0][0]);
      acc[0][1] = MFMA32(af0, vf1, acc[0][1]);
      acc[1][0] = MFMA32(af1, vf0, acc[1][0]);
      acc[1][1] = MFMA32(af1, vf1, acc[1][1]);
      __builtin_amdgcn_s_setprio(0);
    }
    if (kc < 15) asm volatile("s_waitcnt vmcnt(0)");
    __syncthreads();
  }

  // ---- epilogue (shfl version, wrT folded): cs values -> csrow in LDS
  const float lf0 = LR[i * 128 + l31] + Br[l31];
  const float lf1 = LR[i * 128 + 32 + l31] + Br[32 + l31];
  const float wo0 = Wo[l31], wo1 = Wo[32 + l31];
  const int sbi = sb[i];
  const float ssi = ss[i];
  const float bo0 = bo[0];
#pragma unroll
  for (int jf = 0; jf < 2; ++jf) {
#pragma unroll
    for (int r = 0; r < 16; ++r) {
      int j = w * 64 + jf * 32 + (r & 3) + 8 * (r >> 2) + 4 * half;
      int dd = sbi - sb[j];
      int ad = dd < 0 ? -dd : dd;
      int bkt = ad < 5 ? ad : (31 - __clz(ad)) + 3;
      bkt = bkt > 9 ? 9 : bkt;
      float v0 = fmaxf(acc[jf][0][r] + lf0 + dts[bkt * 64 + l31], 0.f);
      float v1 = fmaxf(acc[jf][1][r] + lf1 + dts[bkt * 64 + 32 + l31], 0.f);
      float sum = v0 * wo0 + v1 * wo1;
      sum += __shfl_xor(sum, 1);
      sum += __shfl_xor(sum, 2);
      sum += __shfl_xor(sum, 4);
      sum += __shfl_xor(sum, 8);
      sum += __shfl_xor(sum, 16);
      if (l31 == 0)
        csrow[j] = (j == i) ? 0.f : (sum + bo0 + ssi + ss[j]);
    }
  }
  __syncthreads();

  if (dosm) {
    // waves 0/1: masked softmax of csrow -> p12 rows (kind = wave)
    if (w < 2) {
      const int kind = w;
      float v[8];
      float4 x0 = *(const float4*)&csrow[l * 8];
      float4 x1 = *(const float4*)&csrow[l * 8 + 4];
      v[0] = x0.x; v[1] = x0.y; v[2] = x0.z; v[3] = x0.w;
      v[4] = x1.x; v[5] = x1.y; v[6] = x1.z; v[7] = x1.w;
      bool any = (kind == 0) ? (i > 0) : (i < 511);
      bf16x8 ov;
      if (!any) {
        float u = 1.0f / 512.0f;
#pragma unroll
        for (int e = 0; e < 8; ++e) ov[e] = (bf16)u;
      } else {
        float m = -3.4e38f;
#pragma unroll
        for (int e = 0; e < 8; ++e) {
          int jj = l * 8 + e;
          bool valid = (kind == 0) ? (jj < i) : (jj > i);
          if (valid) m = fmaxf(m, v[e]);
        }
        m = fmaxf(m, __shfl_xor(m, 1));  m = fmaxf(m, __shfl_xor(m, 2));
        m = fmaxf(m, __shfl_xor(m, 4));  m = fmaxf(m, __shfl_xor(m, 8));
        m = fmaxf(m, __shfl_xor(m, 16)); m = fmaxf(m, __shfl_xor(m, 32));
        float p[8]; float ssum = 0.f;
#pragma unroll
        for (int e = 0; e < 8; ++e) {
          int jj = l * 8 + e;
          bool valid = (kind == 0) ? (jj < i) : (jj > i);
          p[e] = valid ? __expf(v[e] - m) : 0.f;
          ssum += p[e];
        }
        ssum += __shfl_xor(ssum, 1);  ssum += __shfl_xor(ssum, 2);
        ssum += __shfl_xor(ssum, 4);  ssum += __shfl_xor(ssum, 8);
        ssum += __shfl_xor(ssum, 16); ssum += __shfl_xor(ssum, 32);
        float inv = 1.0f / ssum;
#pragma unroll
        for (int e = 0; e < 8; ++e) ov[e] = (bf16)(p[e] * inv);
      }
      *(bf16x8*)(p12 + ((long)kind * 512 + i) * 512 + l * 8) = ov;
    }
  } else {
    // coalesced cs row write
    cs[(long)i * 512 + t] = csrow[t];
  }

  // ---- folded FULL all_span_vecs copy (pair1 only; must precede mid2's scatter)
  if (docopy) {
    const float4* s4 = (const float4*)copysrc;
    float4* d4 = (float4*)copydst;
    int idx = i * 512 + t;               // 262144 threads
#pragma unroll
    for (int q = 0; q < 8; ++q)
      d4[(long)q * 262144 + idx] = s4[(long)q * 262144 + idx];
  }
}

// ---------------------------------------------------------------- mid2: gate+ss2+lr2+scatter
__global__ __launch_bounds__(512) void k_mid2(
    const float* __restrict__ sv, const float* __restrict__ c12,
    const float* __restrict__ G12, const float* __restrict__ Wpr,
    const float* __restrict__ bpr, const bf16* __restrict__ wlr,
    const float* __restrict__ blbr, const int* __restrict__ pi,
    const int* __restrict__ sl, float* __restrict__ upd,
    bf16* __restrict__ u2, float* __restrict__ ss2,
    float* __restrict__ lr2, float* __restrict__ out_all)
{
  __shared__ float upl[512];
  __shared__ float red[8];
  __shared__ float part2[4][128];
  const int i = blockIdx.x;
  const int t = threadIdx.x;
  const long ii = (long)i * 512 + t;

  float u = sv[ii], c1 = c12[ii], c2 = c12[262144 + ii];
  float g1 = 1.f / (1.f + __expf(-G12[ii]));
  float g2 = 1.f / (1.f + __expf(-G12[262144 + ii]));
  float up = g1 * u + (1.f - g1) * c1 + g2 * u + (1.f - g2) * c2;
  upd[ii] = up;
  u2[ii] = (bf16)up;
  upl[t] = up;
  if (i < sl[0]) out_all[(long)pi[i] * 512 + t] = up;   // scatter (out_all pre-filled)

  // ss2 = dot(up, Wpr) + bpr
  float pd = up * Wpr[t];
  pd += __shfl_xor(pd, 1);  pd += __shfl_xor(pd, 2);  pd += __shfl_xor(pd, 4);
  pd += __shfl_xor(pd, 8);  pd += __shfl_xor(pd, 16); pd += __shfl_xor(pd, 32);
  if ((t & 63) == 0) red[t >> 6] = pd;
  __syncthreads();
  if (t == 0) {
    float s = 0.f;
#pragma unroll
    for (int e = 0; e < 8; ++e) s += red[e];
    ss2[i] = s + bpr[0];
  }

  // lr2[i][n] = sum_d up[d]*wlr[d][n] + blbr[n]
  const int n = t & 127, part = t >> 7;
  float s = 0.f;
  const int d0 = part * 128;
#pragma unroll 4
  for (int d2 = 0; d2 < 128; ++d2)
    s += upl[d0 + d2] * (float)wlr[(d0 + d2) * 128 + n];
  part2[part][n] = s;
  __syncthreads();
  if (t < 128)
    lr2[(long)i * 128 + t] =
        part2[0][t] + part2[1][t] + part2[2][t] + part2[3][t] + blbr[t];
}

// ---------------------------------------------------------------- launch
extern "C" void kernel_launch(void* const* d_in, const int* in_sizes, int n_in,
                              void* d_out, int out_size, void* d_ws, size_t ws_size,
                              hipStream_t stream)
{
  const float* asv = (const float*)d_in[0];
  const float* sv = (const float*)d_in[1];
  const int* sb = (const int*)d_in[2];
  const float* sscore = (const float*)d_in[5];
  const int* pi = (const int*)d_in[6];
  const int* sl = (const int*)d_in[7];
  const float* Wl = (const float*)d_in[9];
  const float* bl = (const float*)d_in[10];
  const float* Wr = (const float*)d_in[11];
  const float* br = (const float*)d_in[12];
  const float* Wp = (const float*)d_in[13];
  const float* de = (const float*)d_in[14];
  const float* Wd = (const float*)d_in[15];
  const float* bd = (const float*)d_in[16];
  const float* Wo = (const float*)d_in[17];
  const float* bo = (const float*)d_in[18];
  const float* Wg1 = (const float*)d_in[19];
  const float* bg1 = (const float*)d_in[20];
  const float* Wg2 = (const float*)d_in[21];
  const float* bg2 = (const float*)d_in[22];
  const float* Wpr = (const float*)d_in[23];
  const float* bpr = (const float*)d_in[24];

  float* out_all = (float*)d_out;
  float* out_upd = out_all + 8388608;   // [512][512] update
  float* out_cs = out_all + 8650752;    // [512][512] cs

  char* w = (char*)d_ws;
  size_t off = 0;
  auto take = [&](size_t bytes) -> void* {
    void* p = w + off;
    off = (off + bytes + 255) & ~(size_t)255;
    return p;
  };
  bf16* u1b = (bf16*)take(524288);
  bf16* u2b = (bf16*)take(524288);
  bf16* wlr = (bf16*)take(131072);
  bf16* wgb = (bf16*)take(2097152);
  float* blbr = (float*)take(512);
  float* bgc = (float*)take(4096);
  float* dtab = (float*)take(2560);
  bf16* wpTb = (bf16*)take(65536);
  bf16* wrTb = (bf16*)take(65536);
  float* lr1 = (float*)take(262144);
  float* lr2 = (float*)take(262144);
  bf16* p12 = (bf16*)take(1048576);
  float* c12 = (float*)take(4194304);
  bf16* ugb = (bf16*)take(2097152);
  float* G12 = (float*)take(2097152);
  float* ss2 = (float*)take(2048);

  k_prep<<<2048, 256, 0, stream>>>(sv, Wl, Wr, Wg1, Wg2, de, Wd, bd, bl, br, bg1, bg2,
                                   Wp, u1b, ugb, wlr, blbr, bgc, wgb, dtab, wpTb, wrTb);
  // left|right for u
  k_gemm<<<dim3(2, 8, 1), 256, 0, stream>>>(u1b, 512, 0, wlr, 128, 0, lr1, 128, 0,
                                            blbr, 0, 512, nullptr);
  // pair1: softmax fused -> p12 directly; + full all_out copy (pre-scatter)
  k_pair<<<512, 512, 0, stream>>>(u1b, sv, wpTb, wrTb, lr1, dtab, sb, sscore, Wo, bo,
                                  br, nullptr, p12, 1, asv, out_all, 1);
  // c1,c2 = [p1;p2] @ u ; epilogue also fills ugb right halves (bf16)
  k_gemm<<<dim3(8, 16, 1), 256, 0, stream>>>(p12, 512, 0, u1b, 512, 0, c12, 512, 0,
                                             nullptr, 0, 512, ugb);
  // G1,G2 = [u|c] @ Wg + bg   (batched z=2, K=1024)
  k_gemm<<<dim3(8, 8, 2), 256, 0, stream>>>(ugb, 1024, 524288, wgb, 512, 524288,
                                            G12, 512, 262144, bgc, 512, 1024, nullptr);
  // update + u2 bf16 + ss2 + lr2 + scatter (fused)
  k_mid2<<<512, 512, 0, stream>>>(sv, c12, G12, Wpr, bpr, wlr, blbr, pi, sl,
                                  out_upd, u2b, ss2, lr2, out_all);
  // pair2: cs = add_scores(pair_scores(update), update@Wpr+bpr) -> out_cs (coalesced)
  k_pair<<<512, 512, 0, stream>>>(u2b, out_upd, wpTb, wrTb, lr2, dtab, sb, ss2, Wo, bo,
                                  br, out_cs, nullptr, 0, nullptr, nullptr, 0);
}

// Round 10
// 148.084 us; speedup vs baseline: 1.2579x; 1.0705x over previous
//
#include <hip/hip_runtime.h>
#include <hip/hip_bf16.h>

// ModuleCorefProp2: coref propagation, B=1, K=512, N=16384, D=512, H=64, NB=10, 1 iter.
// R10: k_pair restructured as a standard 256x256-tile GEMM over M=(i,h)=32768, N=j=512,
// K=d=512. A-panel rows (i,h) built on the fly (U[i,d]*WpT[h,d]); B-panel = U rows via
// pre-swizzled global_load_lds. h-reduce in-register (+1 shfl). LDS bytes/MFMA -40%,
// gll traffic /4, VALU-build /4. Softmax back to standalone kernel (cs1 roundtrip).

typedef __bf16 bf16;
typedef bf16 bf16x8 __attribute__((ext_vector_type(8)));
typedef float f32x4 __attribute__((ext_vector_type(4)));
typedef float f32x16 __attribute__((ext_vector_type(16)));

#define MFMA16(a, b, c) __builtin_amdgcn_mfma_f32_16x16x32_bf16((a), (b), (c), 0, 0, 0)
#define MFMA32(a, b, c) __builtin_amdgcn_mfma_f32_32x32x16_bf16((a), (b), (c), 0, 0, 0)

__device__ __forceinline__ void gll16(const bf16* g, bf16* lds) {
  __builtin_amdgcn_global_load_lds(
      (const __attribute__((address_space(1))) unsigned int*)g,
      (__attribute__((address_space(3))) unsigned int*)lds, 16, 0, 0);
}

// ---------------------------------------------------------------- prep
__global__ void k_prep(const float* __restrict__ sv,
                       const float* __restrict__ Wl, const float* __restrict__ Wr,
                       const float* __restrict__ Wg1, const float* __restrict__ Wg2,
                       const float* __restrict__ de, const float* __restrict__ Wd,
                       const float* __restrict__ bd, const float* __restrict__ bl,
                       const float* __restrict__ br, const float* __restrict__ bg1,
                       const float* __restrict__ bg2, const float* __restrict__ Wp,
                       bf16* __restrict__ u1, bf16* __restrict__ ugb,
                       bf16* __restrict__ wlr, float* __restrict__ blbr,
                       float* __restrict__ bgc, bf16* __restrict__ wgb,
                       float* __restrict__ dtab, bf16* __restrict__ wpTb)
{
  const int total = 262144 + 65536 + 128 + 1048576 + 1024 + 640 + 32768;
  for (int idx0 = blockIdx.x * 256 + threadIdx.x; idx0 < total; idx0 += 2048 * 256) {
    int k = idx0;
    if (k < 262144) {                 // u -> bf16, and left halves of gate inputs
      float v = sv[k]; bf16 b = (bf16)v; u1[k] = b;
      int i = k >> 9, d = k & 511;
      ugb[(long)i * 1024 + d] = b;
      ugb[524288 + (long)i * 1024 + d] = b;
      continue;
    }
    k -= 262144;
    if (k < 65536) {                  // Wlr = [Wl | Wr] bf16 [512][128]
      int d = k >> 7, h = k & 127;
      wlr[k] = (bf16)(h < 64 ? Wl[d * 64 + h] : Wr[d * 64 + h - 64]);
      continue;
    }
    k -= 65536;
    if (k < 128) { blbr[k] = (k < 64 ? bl[k] : br[k - 64]); continue; }
    k -= 128;
    if (k < 1048576) {                // Wg1|Wg2 bf16 [2][1024][512]
      wgb[k] = (bf16)(k < 524288 ? Wg1[k] : Wg2[k - 524288]);
      continue;
    }
    k -= 1048576;
    if (k < 1024) { bgc[k] = (k < 512 ? bg1[k] : bg2[k - 512]); continue; }
    k -= 1024;
    if (k < 640) {                    // dtab[NB][64] = dist_emb@Wd + bd
      int b_ = k >> 6, h = k & 63;
      float s = bd[h];
      for (int e = 0; e < 64; ++e) s += de[b_ * 64 + e] * Wd[e * 64 + h];
      dtab[k] = s;
      continue;
    }
    k -= 640;
    {                                 // wpTb[h][d] = Wp[d][h], bf16 [64][512]
      int h = k >> 9, d = k & 511;
      wpTb[k] = (bf16)Wp[d * 64 + h];
    }
  }
}

// ---------------------------------------------------------------- generic GEMM
__global__ __launch_bounds__(256, 2) void k_gemm(
    const bf16* __restrict__ A, int lda, long asz,
    const bf16* __restrict__ B, int ldb, long bsz,
    float* __restrict__ C, int ldc, long csz,
    const float* __restrict__ bias, int bstride, int K,
    bf16* __restrict__ xout)
{
  __shared__ bf16 As[64 * 40];
  __shared__ bf16 Bs[64 * 40];
  const int t = threadIdx.x, lane = t & 63, wave = t >> 6;
  const int tc = blockIdx.x, tr = blockIdx.y, z = blockIdx.z;
  A += (long)z * asz; B += (long)z * bsz; C += (long)z * csz;
  const int wr = wave >> 1, wc = wave & 1;
  const int arow = t >> 2, aslot = t & 3;
  const int s = lane >> 4, rr = lane & 15;
  f32x4 acc00 = {}, acc01 = {}, acc10 = {}, acc11 = {};
  const int nk = K >> 5;
  for (int kk = 0; kk < nk; ++kk) {
    __syncthreads();
    *(uint4*)&As[arow * 40 + aslot * 8] =
        *(const uint4*)(A + (long)(tr * 64 + arow) * lda + kk * 32 + aslot * 8);
    {
      const bf16* bsrc = B + (long)(kk * 32 + aslot * 8) * ldb + tc * 64 + arow;
      bf16x8 tv;
#pragma unroll
      for (int e = 0; e < 8; ++e) tv[e] = bsrc[(long)e * ldb];
      *(bf16x8*)&Bs[arow * 40 + aslot * 8] = tv;
    }
    __syncthreads();
    bf16x8 a0 = *(const bf16x8*)&As[(wr * 32 + rr) * 40 + s * 8];
    bf16x8 a1 = *(const bf16x8*)&As[(wr * 32 + 16 + rr) * 40 + s * 8];
    bf16x8 b0 = *(const bf16x8*)&Bs[(wc * 32 + rr) * 40 + s * 8];
    bf16x8 b1 = *(const bf16x8*)&Bs[(wc * 32 + 16 + rr) * 40 + s * 8];
    acc00 = MFMA16(a0, b0, acc00);
    acc01 = MFMA16(a0, b1, acc01);
    acc10 = MFMA16(a1, b0, acc10);
    acc11 = MFMA16(a1, b1, acc11);
  }
#pragma unroll
  for (int mf = 0; mf < 2; ++mf) {
#pragma unroll
    for (int nf = 0; nf < 2; ++nf) {
      f32x4 v = mf == 0 ? (nf == 0 ? acc00 : acc01) : (nf == 0 ? acc10 : acc11);
      int col = tc * 64 + wc * 32 + nf * 16 + rr;
      float bi = bias ? bias[z * bstride + col] : 0.f;
      int row0 = tr * 64 + wr * 32 + mf * 16 + s * 4;
#pragma unroll
      for (int r = 0; r < 4; ++r) {
        float val = v[r] + bi;
        int row = row0 + r;
        C[(long)row * ldc + col] = val;
        if (xout) {
          long gidx = (row < 512)
              ? ((long)row * 1024 + 512 + col)
              : (524288 + (long)(row - 512) * 1024 + 512 + col);
          xout[gidx] = (bf16)val;
        }
      }
    }
  }
}

// ---------------------------------------------------------------- fused pair scorer (R10)
// GEMM over M=(i,h)=32768 rows, N=j=512, K=d=512. Tile 256x256, grid (jb=2, mt=128),
// 512 thr = 8 waves (wm=w>>1 owns i=mt*4+wm i.e. 64 h-rows; wn=w&1 owns 128 j-cols).
// A-panel[256r x 32k] built on the fly: row (ii,h): Uf[i0+ii,d]*WpT[h,d] (bf16, swizzled).
// B-panel[256r x 32k] = U j-rows via gll (pre-swizzled source). Dbuf, 1 barrier/chunk.
// Epilogue: in-register h-reduce: relu(acc + left + right + dist)*Wo summed over 16 regs
// + one shfl_xor(32); coalesced cs row-segment writes.
__global__ __launch_bounds__(512, 2) void k_pair(
    const bf16* __restrict__ Ubf, const float* __restrict__ Uf,
    const bf16* __restrict__ wpTb, const float* __restrict__ LR,
    const float* __restrict__ dtabg, const int* __restrict__ sb,
    const float* __restrict__ ss, const float* __restrict__ Wo,
    const float* __restrict__ bo, float* __restrict__ cs,
    const float* __restrict__ copysrc, float* __restrict__ copydst, int docopy)
{
  __shared__ bf16 Apan[2][256 * 32];   // 2 x 16KB
  __shared__ bf16 Bpan[2][256 * 32];   // 2 x 16KB
  __shared__ float dtsp[10 * 68];      // padded dist table
  __shared__ int sbt[256];             // sb[j-tile]

  const int t = threadIdx.x;
  const int l = t & 63;
  const int w = t >> 6;
  const int wm = w >> 1, wn = w & 1;
  const int hi = l >> 5, l31 = l & 31;
  const int jb = blockIdx.x;           // 0..1
  const int mt = blockIdx.y;           // 0..127
  const int i0 = mt * 4;
  const int i = i0 + wm;

  // ---- prologue: tables
  for (int idx = t; idx < 640; idx += 512)
    dtsp[(idx >> 6) * 68 + (idx & 63)] = dtabg[idx];
  if (t < 256) sbt[t] = sb[jb * 256 + t];

  // B gll sources (2 units/thread): unit u = q*512+t -> row u>>2, slot u&3
  const bf16 *bsrc0, *bsrc1;
  {
    int r0 = t >> 2, c0 = t & 3;
    int r1 = 128 + (t >> 2);
    bsrc0 = Ubf + (long)(jb * 256 + r0) * 512 + ((c0 ^ ((r0 >> 1) & 3)) * 8);
    bsrc1 = Ubf + (long)(jb * 256 + r1) * 512 + ((c0 ^ ((r1 >> 1) & 3)) * 8);
  }
  // A build (2 units/thread): rows t>>2 and 128+(t>>2), slot t&3
  const int ar0 = t >> 2, ar1 = 128 + (t >> 2), as0 = t & 3;
  const int awb0 = ar0 * 64 + ((as0 ^ ((ar0 >> 1) & 3)) * 16);   // byte offsets
  const int awb1 = ar1 * 64 + ((as0 ^ ((ar1 >> 1) & 3)) * 16);
  const float* ua0p = Uf + (long)(i0 + (ar0 >> 6)) * 512 + as0 * 8;
  const float* ua1p = Uf + (long)(i0 + (ar1 >> 6)) * 512 + as0 * 8;
  const bf16* wp0p = wpTb + (long)(ar0 & 63) * 512 + as0 * 8;
  const bf16* wp1p = wpTb + (long)(ar1 & 63) * 512 + as0 * 8;

  // fragment read byte-offsets
  int aoff[2][2], boff[4][2];
#pragma unroll
  for (int rf = 0; rf < 2; ++rf)
#pragma unroll
    for (int ks = 0; ks < 2; ++ks) {
      int r = wm * 64 + rf * 32 + l31;
      aoff[rf][ks] = r * 64 + (((ks * 2 + hi) ^ ((r >> 1) & 3)) * 16);
    }
#pragma unroll
  for (int cf = 0; cf < 4; ++cf)
#pragma unroll
    for (int ks = 0; ks < 2; ++ks) {
      int r = wn * 128 + cf * 32 + l31;
      boff[cf][ks] = r * 64 + (((ks * 2 + hi) ^ ((r >> 1) & 3)) * 16);
    }

  // ---- stage chunk 0 into buf 0
  {
    gll16(bsrc0, &Bpan[0][0 * 4096 + w * 512]);
    gll16(bsrc1, &Bpan[0][1 * 4096 + w * 512]);
    float4 a00 = *(const float4*)ua0p, a01 = *(const float4*)(ua0p + 4);
    float4 a10 = *(const float4*)ua1p, a11 = *(const float4*)(ua1p + 4);
    bf16x8 w0 = *(const bf16x8*)wp0p, w1 = *(const bf16x8*)wp1p;
    bf16x8 v0, v1;
#pragma unroll
    for (int e = 0; e < 4; ++e) {
      v0[e] = (bf16)(a00[e] * (float)w0[e]);
      v0[e + 4] = (bf16)(a01[e] * (float)w0[e + 4]);
      v1[e] = (bf16)(a10[e] * (float)w1[e]);
      v1[e + 4] = (bf16)(a11[e] * (float)w1[e + 4]);
    }
    *(bf16x8*)((char*)&Apan[0][0] + awb0) = v0;
    *(bf16x8*)((char*)&Apan[0][0] + awb1) = v1;
  }
  asm volatile("s_waitcnt vmcnt(0)");
  __syncthreads();

  f32x16 acc[2][4] = {};

  for (int kc = 0; kc < 16; ++kc) {
    const int cur = kc & 1;
    float4 nA00, nA01, nA10, nA11;
    bf16x8 nW0, nW1;
    if (kc < 15) {                    // issue next-chunk loads (hide under compute)
      gll16(bsrc0 + (kc + 1) * 32, &Bpan[cur ^ 1][0 * 4096 + w * 512]);
      gll16(bsrc1 + (kc + 1) * 32, &Bpan[cur ^ 1][1 * 4096 + w * 512]);
      nA00 = *(const float4*)(ua0p + (kc + 1) * 32);
      nA01 = *(const float4*)(ua0p + (kc + 1) * 32 + 4);
      nA10 = *(const float4*)(ua1p + (kc + 1) * 32);
      nA11 = *(const float4*)(ua1p + (kc + 1) * 32 + 4);
      nW0 = *(const bf16x8*)(wp0p + (kc + 1) * 32);
      nW1 = *(const bf16x8*)(wp1p + (kc + 1) * 32);
    }
    // compute chunk kc
    const char* Ab = (const char*)&Apan[cur][0];
    const char* Bb = (const char*)&Bpan[cur][0];
#pragma unroll
    for (int ks = 0; ks < 2; ++ks) {
      bf16x8 af0 = *(const bf16x8*)(Ab + aoff[0][ks]);
      bf16x8 af1 = *(const bf16x8*)(Ab + aoff[1][ks]);
      bf16x8 bf0 = *(const bf16x8*)(Bb + boff[0][ks]);
      bf16x8 bf1 = *(const bf16x8*)(Bb + boff[1][ks]);
      bf16x8 bf2 = *(const bf16x8*)(Bb + boff[2][ks]);
      bf16x8 bf3 = *(const bf16x8*)(Bb + boff[3][ks]);
      __builtin_amdgcn_s_setprio(1);
      acc[0][0] = MFMA32(af0, bf0, acc[0][0]);
      acc[0][1] = MFMA32(af0, bf1, acc[0][1]);
      acc[0][2] = MFMA32(af0, bf2, acc[0][2]);
      acc[0][3] = MFMA32(af0, bf3, acc[0][3]);
      acc[1][0] = MFMA32(af1, bf0, acc[1][0]);
      acc[1][1] = MFMA32(af1, bf1, acc[1][1]);
      acc[1][2] = MFMA32(af1, bf2, acc[1][2]);
      acc[1][3] = MFMA32(af1, bf3, acc[1][3]);
      __builtin_amdgcn_s_setprio(0);
    }
    if (kc < 15) {
      asm volatile("s_waitcnt vmcnt(0)");  // gll B landed; A loads in regs
      bf16x8 v0, v1;
#pragma unroll
      for (int e = 0; e < 4; ++e) {
        v0[e] = (bf16)(nA00[e] * (float)nW0[e]);
        v0[e + 4] = (bf16)(nA01[e] * (float)nW0[e + 4]);
        v1[e] = (bf16)(nA10[e] * (float)nW1[e]);
        v1[e + 4] = (bf16)(nA11[e] * (float)nW1[e + 4]);
      }
      *(bf16x8*)((char*)&Apan[cur ^ 1][0] + awb0) = v0;
      *(bf16x8*)((char*)&Apan[cur ^ 1][0] + awb1) = v1;
    }
    __syncthreads();
  }

  // ---- epilogue: cs[i][j] = (i==j)?0 : sum_h Wo[h]*relu(acc+left+right+dist)+bo+ss_i+ss_j
  // h for reg r (within rowfrag rf): h = rf*32 + (r&3) + 8*(r>>2) + 4*hi
  float4 wo_t[2][4], lf_t[2][4];
#pragma unroll
  for (int rf = 0; rf < 2; ++rf)
#pragma unroll
    for (int g = 0; g < 4; ++g) {
      wo_t[rf][g] = *(const float4*)&Wo[rf * 32 + 4 * hi + 8 * g];
      lf_t[rf][g] = *(const float4*)&LR[i * 128 + rf * 32 + 4 * hi + 8 * g];
    }
  const float ssi = ss[i];
  const int sbi = sb[i];
  const float bo0 = bo[0];
#pragma unroll
  for (int cf = 0; cf < 4; ++cf) {
    int jl = wn * 128 + cf * 32 + l31;
    int j = jb * 256 + jl;
    int dd = sbi - sbt[jl];
    int ad = dd < 0 ? -dd : dd;
    int bkt = ad < 5 ? ad : (31 - __clz(ad)) + 3;
    bkt = bkt > 9 ? 9 : bkt;
    float ssj = ss[j];
    float sum = 0.f;
#pragma unroll
    for (int rf = 0; rf < 2; ++rf) {
#pragma unroll
      for (int g = 0; g < 4; ++g) {
        float4 dt4 = *(const float4*)&dtsp[bkt * 68 + rf * 32 + 4 * hi + 8 * g];
        float4 rt4 = *(const float4*)&LR[j * 128 + 64 + rf * 32 + 4 * hi + 8 * g];
#pragma unroll
        for (int e = 0; e < 4; ++e) {
          float v = acc[rf][cf][g * 4 + e] + lf_t[rf][g][e] + rt4[e] + dt4[e];
          v = fmaxf(v, 0.f);
          sum += v * wo_t[rf][g][e];
        }
      }
    }
    sum += __shfl_xor(sum, 32);
    float val = (j == i) ? 0.f : (sum + bo0 + ssi + ssj);
    if (hi == 0) cs[(long)i * 512 + j] = val;
  }

  // ---- folded FULL all_span_vecs copy (pair1 only; must precede mid2's scatter)
  if (docopy) {
    const float4* s4 = (const float4*)copysrc;
    float4* d4 = (float4*)copydst;
    int idx = (mt * 2 + jb) * 512 + t;   // 131072 threads
#pragma unroll
    for (int q = 0; q < 16; ++q)
      d4[(long)q * 131072 + idx] = s4[(long)q * 131072 + idx];
  }
}

// ---------------------------------------------------------------- masked softmax rows
__global__ __launch_bounds__(64) void k_softmax(const float* __restrict__ cs,
                                                bf16* __restrict__ p12)
{
  int b = blockIdx.x, kind = b >> 9, i = b & 511, lane = threadIdx.x;
  const float* row = cs + i * 512;
  float v[8];
  float4 x0 = *(const float4*)(row + lane * 8);
  float4 x1 = *(const float4*)(row + lane * 8 + 4);
  v[0] = x0.x; v[1] = x0.y; v[2] = x0.z; v[3] = x0.w;
  v[4] = x1.x; v[5] = x1.y; v[6] = x1.z; v[7] = x1.w;
  bool any = (kind == 0) ? (i > 0) : (i < 511);
  bf16x8 ov;
  if (!any) {
    float u = 1.0f / 512.0f;
#pragma unroll
    for (int e = 0; e < 8; ++e) ov[e] = (bf16)u;
  } else {
    float m = -3.4e38f;
#pragma unroll
    for (int e = 0; e < 8; ++e) {
      int jj = lane * 8 + e;
      bool valid = (kind == 0) ? (jj < i) : (jj > i);
      if (valid) m = fmaxf(m, v[e]);
    }
    m = fmaxf(m, __shfl_xor(m, 1));  m = fmaxf(m, __shfl_xor(m, 2));
    m = fmaxf(m, __shfl_xor(m, 4));  m = fmaxf(m, __shfl_xor(m, 8));
    m = fmaxf(m, __shfl_xor(m, 16)); m = fmaxf(m, __shfl_xor(m, 32));
    float p[8]; float ssum = 0.f;
#pragma unroll
    for (int e = 0; e < 8; ++e) {
      int jj = lane * 8 + e;
      bool valid = (kind == 0) ? (jj < i) : (jj > i);
      p[e] = valid ? __expf(v[e] - m) : 0.f;
      ssum += p[e];
    }
    ssum += __shfl_xor(ssum, 1);  ssum += __shfl_xor(ssum, 2);
    ssum += __shfl_xor(ssum, 4);  ssum += __shfl_xor(ssum, 8);
    ssum += __shfl_xor(ssum, 16); ssum += __shfl_xor(ssum, 32);
    float inv = 1.0f / ssum;
#pragma unroll
    for (int e = 0; e < 8; ++e) ov[e] = (bf16)(p[e] * inv);
  }
  *(bf16x8*)(p12 + (long)b * 512 + lane * 8) = ov;
}

// ---------------------------------------------------------------- mid2: gate+ss2+lr2+scatter
__global__ __launch_bounds__(512) void k_mid2(
    const float* __restrict__ sv, const float* __restrict__ c12,
    const float* __restrict__ G12, const float* __restrict__ Wpr,
    const float* __restrict__ bpr, const bf16* __restrict__ wlr,
    const float* __restrict__ blbr, const int* __restrict__ pi,
    const int* __restrict__ sl, float* __restrict__ upd,
    bf16* __restrict__ u2, float* __restrict__ ss2,
    float* __restrict__ lr2, float* __restrict__ out_all)
{
  __shared__ float upl[512];
  __shared__ float red[8];
  __shared__ float part2[4][128];
  const int i = blockIdx.x;
  const int t = threadIdx.x;
  const long ii = (long)i * 512 + t;

  float u = sv[ii], c1 = c12[ii], c2 = c12[262144 + ii];
  float g1 = 1.f / (1.f + __expf(-G12[ii]));
  float g2 = 1.f / (1.f + __expf(-G12[262144 + ii]));
  float up = g1 * u + (1.f - g1) * c1 + g2 * u + (1.f - g2) * c2;
  upd[ii] = up;
  u2[ii] = (bf16)up;
  upl[t] = up;
  if (i < sl[0]) out_all[(long)pi[i] * 512 + t] = up;   // scatter (out_all pre-filled)

  // ss2 = dot(up, Wpr) + bpr
  float pd = up * Wpr[t];
  pd += __shfl_xor(pd, 1);  pd += __shfl_xor(pd, 2);  pd += __shfl_xor(pd, 4);
  pd += __shfl_xor(pd, 8);  pd += __shfl_xor(pd, 16); pd += __shfl_xor(pd, 32);
  if ((t & 63) == 0) red[t >> 6] = pd;
  __syncthreads();
  if (t == 0) {
    float s = 0.f;
#pragma unroll
    for (int e = 0; e < 8; ++e) s += red[e];
    ss2[i] = s + bpr[0];
  }

  // lr2[i][n] = sum_d up[d]*wlr[d][n] + blbr[n]
  const int n = t & 127, part = t >> 7;
  float s = 0.f;
  const int d0 = part * 128;
#pragma unroll 4
  for (int d2 = 0; d2 < 128; ++d2)
    s += upl[d0 + d2] * (float)wlr[(d0 + d2) * 128 + n];
  part2[part][n] = s;
  __syncthreads();
  if (t < 128)
    lr2[(long)i * 128 + t] =
        part2[0][t] + part2[1][t] + part2[2][t] + part2[3][t] + blbr[t];
}

// ---------------------------------------------------------------- launch
extern "C" void kernel_launch(void* const* d_in, const int* in_sizes, int n_in,
                              void* d_out, int out_size, void* d_ws, size_t ws_size,
                              hipStream_t stream)
{
  const float* asv = (const float*)d_in[0];
  const float* sv = (const float*)d_in[1];
  const int* sb = (const int*)d_in[2];
  const float* sscore = (const float*)d_in[5];
  const int* pi = (const int*)d_in[6];
  const int* sl = (const int*)d_in[7];
  const float* Wl = (const float*)d_in[9];
  const float* bl = (const float*)d_in[10];
  const float* Wr = (const float*)d_in[11];
  const float* br = (const float*)d_in[12];
  const float* Wp = (const float*)d_in[13];
  const float* de = (const float*)d_in[14];
  const float* Wd = (const float*)d_in[15];
  const float* bd = (const float*)d_in[16];
  const float* Wo = (const float*)d_in[17];
  const float* bo = (const float*)d_in[18];
  const float* Wg1 = (const float*)d_in[19];
  const float* bg1 = (const float*)d_in[20];
  const float* Wg2 = (const float*)d_in[21];
  const float* bg2 = (const float*)d_in[22];
  const float* Wpr = (const float*)d_in[23];
  const float* bpr = (const float*)d_in[24];

  float* out_all = (float*)d_out;
  float* out_upd = out_all + 8388608;   // [512][512] update
  float* out_cs = out_all + 8650752;    // [512][512] cs

  char* w = (char*)d_ws;
  size_t off = 0;
  auto take = [&](size_t bytes) -> void* {
    void* p = w + off;
    off = (off + bytes + 255) & ~(size_t)255;
    return p;
  };
  bf16* u1b = (bf16*)take(524288);
  bf16* u2b = (bf16*)take(524288);
  bf16* wlr = (bf16*)take(131072);
  bf16* wgb = (bf16*)take(2097152);
  float* blbr = (float*)take(512);
  float* bgc = (float*)take(4096);
  float* dtab = (float*)take(2560);
  bf16* wpTb = (bf16*)take(65536);
  float* lr1 = (float*)take(262144);
  float* lr2 = (float*)take(262144);
  float* cs1 = (float*)take(1048576);
  bf16* p12 = (bf16*)take(1048576);
  float* c12 = (float*)take(4194304);
  bf16* ugb = (bf16*)take(2097152);
  float* G12 = (float*)take(2097152);
  float* ss2 = (float*)take(2048);

  k_prep<<<2048, 256, 0, stream>>>(sv, Wl, Wr, Wg1, Wg2, de, Wd, bd, bl, br, bg1, bg2,
                                   Wp, u1b, ugb, wlr, blbr, bgc, wgb, dtab, wpTb);
  // left|right for u
  k_gemm<<<dim3(2, 8, 1), 256, 0, stream>>>(u1b, 512, 0, wlr, 128, 0, lr1, 128, 0,
                                            blbr, 0, 512, nullptr);
  // cs1 = add_scores(pair_scores(u), span_scores); + full all_out copy (pre-scatter)
  k_pair<<<dim3(2, 128), 512, 0, stream>>>(u1b, sv, wpTb, lr1, dtab, sb, sscore, Wo,
                                           bo, cs1, asv, out_all, 1);
  // p1,p2
  k_softmax<<<1024, 64, 0, stream>>>(cs1, p12);
  // c1,c2 = [p1;p2] @ u ; epilogue also fills ugb right halves (bf16)
  k_gemm<<<dim3(8, 16, 1), 256, 0, stream>>>(p12, 512, 0, u1b, 512, 0, c12, 512, 0,
                                             nullptr, 0, 512, ugb);
  // G1,G2 = [u|c] @ Wg + bg   (batched z=2, K=1024)
  k_gemm<<<dim3(8, 8, 2), 256, 0, stream>>>(ugb, 1024, 524288, wgb, 512, 524288,
                                            G12, 512, 262144, bgc, 512, 1024, nullptr);
  // update + u2 bf16 + ss2 + lr2 + scatter (fused)
  k_mid2<<<512, 512, 0, stream>>>(sv, c12, G12, Wpr, bpr, wlr, blbr, pi, sl,
                                  out_upd, u2b, ss2, lr2, out_all);
  // cs = add_scores(pair_scores(update), update@Wpr+bpr) -> out_cs
  k_pair<<<dim3(2, 128), 512, 0, stream>>>(u2b, out_upd, wpTb, lr2, dtab, sb, ss2, Wo,
                                           bo, out_cs, nullptr, nullptr, 0);
}